// Round 7
// baseline (207.602 us; speedup 1.0000x reference)
//
#include <hip/hip_runtime.h>

#define CB 256   // batch
#define CR 1152  // routes
#define CC 10    // class capsules
#define CO 16    // out dim
#define CI 8     // in dim
#define CK (CR*CI)   // 9216
#define NCO (CC*CO)  // 160
#define GRD 160
#define THR 512

typedef __bf16 bf16_t;
typedef __attribute__((ext_vector_type(8))) __bf16 bf16x8;
typedef __attribute__((ext_vector_type(4))) float f32x4;

union SMem {
  float Ls[8][64][4];                 // s-phase partials (8 KB)
  unsigned short vL[NCO][CB + 8];     // asc-phase v staging (84.5 KB)
};

// hand-rolled grid barrier: device-scope atomics on one line, s_sleep poll.
// cnt must be 0 on kernel entry (memset in kernel_launch); returns to 0 after each use.
__device__ __forceinline__ void gbar(unsigned* cnt, unsigned* gen) {
  __syncthreads();
  if (threadIdx.x == 0) {
    __threadfence();                          // release my phase's writes
    const unsigned g = atomicAdd(gen, 0u);    // coherent read
    const unsigned old = atomicAdd(cnt, 1u);  // arrive
    if (old == GRD - 1) {
      atomicExch(cnt, 0u);                    // reset for next use
      __threadfence();
      atomicAdd(gen, 1u);                     // release everyone
    } else {
      while (atomicAdd(gen, 0u) == g) __builtin_amdgcn_s_sleep(1);
    }
    __threadfence();                          // acquire remote writes
  }
  __syncthreads();
}

__global__ __launch_bounds__(THR, 1) void k_fused(
    const float* __restrict__ x, const float* __restrict__ W,
    const float* __restrict__ bias, float* __restrict__ out,
    bf16_t* __restrict__ xb, bf16_t* __restrict__ xTb,
    bf16_t* __restrict__ Wt, bf16_t* __restrict__ Wts,
    bf16_t* __restrict__ vTb, unsigned* __restrict__ bar) {
  __shared__ SMem sm;
  __shared__ float bL[8][CC];     // persistent routing logits (this block's 8 r's)
  __shared__ float agrL[8][CC];
  __shared__ float cwL[8][CC];

  const int blk = blockIdx.x;
  const int t = threadIdx.x;
  const int tid = blk * THR + t;  // 81920 threads

  // ---------------- phase 0: cvt  x->xb [b][k], x->xTb [k][b], W->Wt [co][k] ----------------
  for (int vi = tid; vi < CB * CK / 8; vi += GRD * THR) {
    const float4 f0 = ((const float4*)x)[vi * 2];
    const float4 f1 = ((const float4*)x)[vi * 2 + 1];
    bf16x8 ov;
    ov[0] = (bf16_t)f0.x; ov[1] = (bf16_t)f0.y; ov[2] = (bf16_t)f0.z; ov[3] = (bf16_t)f0.w;
    ov[4] = (bf16_t)f1.x; ov[5] = (bf16_t)f1.y; ov[6] = (bf16_t)f1.z; ov[7] = (bf16_t)f1.w;
    ((bf16x8*)xb)[vi] = ov;
  }
  for (int u = tid; u < CK * (CB / 8); u += GRD * THR) {
    const int k = u % CK, bg = u / CK, b0 = bg * 8;
    bf16x8 tv;
    #pragma unroll
    for (int j = 0; j < 8; ++j) tv[j] = (bf16_t)x[(size_t)(b0 + j) * CK + k];
    *(bf16x8*)(xTb + (size_t)k * CB + b0) = tv;
  }
  for (int wi = tid; wi < NCO * CR; wi += GRD * THR) {
    const int r = wi % CR;
    const int co = wi / CR;
    const int c = co >> 4, o = co & 15;
    const float4* src = (const float4*)(W + (((size_t)r * CC + c) * CO + o) * CI);
    const float4 f0 = src[0], f1 = src[1];
    bf16x8 v;
    v[0] = (bf16_t)f0.x; v[1] = (bf16_t)f0.y; v[2] = (bf16_t)f0.z; v[3] = (bf16_t)f0.w;
    v[4] = (bf16_t)f1.x; v[5] = (bf16_t)f1.y; v[6] = (bf16_t)f1.z; v[7] = (bf16_t)f1.w;
    *(bf16x8*)(Wt + (size_t)co * CK + r * 8) = v;
  }
  gbar(bar, bar + 1);

  for (int it = 0; it < 3; ++it) {
    // ---------------- s + squash: 160 blocks = (bt,c), 8 waves split K ----------------
    {
      const int xcd = blk & 7, j = blk >> 3;
      const int bt = xcd * 2 + (j & 1);
      const int c = j >> 1;
      const int w = t >> 6, lane = t & 63;
      const int mrow = lane & 15, kg = lane >> 4;
      const int b0 = bt * 16;
      const bf16_t* __restrict__ Bmat = (it == 0) ? Wt : Wts;
      const size_t kbase = (size_t)w * (CK / 8);
      const bf16x8* ap = (const bf16x8*)(xb + (size_t)(b0 + mrow) * CK + kbase) + kg;
      const bf16x8* bp = (const bf16x8*)(Bmat + (size_t)(c * CO + mrow) * CK + kbase) + kg;
      f32x4 acc0 = {0.f, 0.f, 0.f, 0.f}, acc1 = {0.f, 0.f, 0.f, 0.f};
      #pragma unroll 6
      for (int s = 0; s < 36; s += 2) {
        acc0 = __builtin_amdgcn_mfma_f32_16x16x32_bf16(ap[s * 4], bp[s * 4], acc0, 0, 0, 0);
        acc1 = __builtin_amdgcn_mfma_f32_16x16x32_bf16(ap[(s + 1) * 4], bp[(s + 1) * 4], acc1, 0, 0, 0);
      }
      const f32x4 acc = acc0 + acc1;
      #pragma unroll
      for (int reg = 0; reg < 4; ++reg) sm.Ls[w][lane][reg] = acc[reg];
      __syncthreads();
      if (t < 256) {
        const int row = t >> 4, col = t & 15;
        const int l = ((row >> 2) << 4) | col, reg = row & 3;
        float s = 0.f;
        #pragma unroll
        for (int q = 0; q < 8; ++q) s += sm.Ls[q][l][reg];
        if (it == 0) s *= 0.1f;          // uniform c_ij = 1/10
        s += bias[c * CO + col];
        float n2 = s * s;
        #pragma unroll
        for (int m = 1; m < 16; m <<= 1) n2 += __shfl_xor(n2, m);
        const float vv = s * n2 / (1.f + n2) * rsqrtf(n2 + 1e-8f);
        if (it == 2) out[(size_t)(b0 + row) * NCO + c * CO + col] = vv;
        else         vTb[(size_t)(c * CO + col) * CB + b0 + row] = (bf16_t)vv;
      }
    }
    if (it == 2) break;
    gbar(bar, bar + 1);

    // ---------------- agree + softmax + prescale: blocks 0..143, class-halves ----------------
    if (blk < 144) {
      const int r0 = blk * 8;
      const int h = t >> 8;
      const int th = t & 255;
      const int w = th >> 6, lane = th & 63;
      const int mrow = lane & 15, kg = lane >> 4;

      #pragma unroll
      for (int q = 0; q < 10; ++q) {     // stage vTb (5120 bf16x8) into LDS
        const int idx = q * THR + t;
        const int co = idx >> 5, bs = idx & 31;
        const bf16x8 v = ((const bf16x8*)vTb)[idx];
        *(bf16x8*)&sm.vL[co][bs * 8] = v;
      }
      const int m0 = r0 * 8 + w * 16;    // A rows (r,i), K = b = 256
      const bf16x8* ap = (const bf16x8*)(xTb + (size_t)(m0 + mrow) * CB) + kg;
      bf16x8 a[8];
      #pragma unroll
      for (int s = 0; s < 8; ++s) a[s] = ap[s * 4];
      __syncthreads();

      const int o = lane & 15, g = lane >> 4;
      #pragma unroll
      for (int cc = 0; cc < 5; ++cc) {
        const int c = h * 5 + cc;
        f32x4 acc = {0.f, 0.f, 0.f, 0.f};
        #pragma unroll
        for (int s = 0; s < 8; ++s) {
          const bf16x8 bv = *(const bf16x8*)&sm.vL[c * CO + mrow][s * 32 + kg * 8];
          acc = __builtin_amdgcn_mfma_f32_16x16x32_bf16(a[s], bv, acc, 0, 0, 0);
        }
        float p = 0.f;
        #pragma unroll
        for (int reg = 0; reg < 4; ++reg) {
          const int m = g * 4 + reg, rl = m >> 3, i = m & 7;
          p += acc[reg] * W[(((size_t)(r0 + w * 2 + rl) * CC + c) * CO + o) * CI + i];
        }
        #pragma unroll
        for (int msk = 1; msk < 32; msk <<= 1) p += __shfl_xor(p, msk);
        if ((lane & 31) == 0) agrL[w * 2 + (lane >> 5)][c] = p * (1.0f / CB);
      }
      __syncthreads();

      if (t < 8) {
        float nb[CC];
        float mx = -1e30f;
        #pragma unroll
        for (int c = 0; c < CC; ++c) {
          nb[c] = (it == 0 ? 0.f : bL[t][c]) + agrL[t][c];
          mx = fmaxf(mx, nb[c]);
        }
        float sum = 0.f;
        #pragma unroll
        for (int c = 0; c < CC; ++c) {
          bL[t][c] = nb[c];
          const float e = __expf(nb[c] - mx);
          cwL[t][c] = e;
          sum += e;
        }
        const float inv = 1.f / sum;
        #pragma unroll
        for (int c = 0; c < CC; ++c) cwL[t][c] *= inv;
      }
      __syncthreads();

      #pragma unroll
      for (int q = 0; q < 3; ++q) {      // Wts = Wt * c_ij for this block's 8 r's
        const int slot = q * THR + t;
        if (slot < 1280) {
          const int co = slot >> 3, rl = slot & 7;
          const float cw = cwL[rl][co >> 4];
          const size_t off = (size_t)co * CK + (r0 + rl) * 8;
          const bf16x8 wv = *(const bf16x8*)(Wt + off);
          bf16x8 ov;
          #pragma unroll
          for (int jj = 0; jj < 8; ++jj) ov[jj] = (bf16_t)((float)wv[jj] * cw);
          *(bf16x8*)(Wts + off) = ov;
        }
      }
    }
    gbar(bar, bar + 1);
  }
}

extern "C" void kernel_launch(void* const* d_in, const int* in_sizes, int n_in,
                              void* d_out, int out_size, void* d_ws, size_t ws_size,
                              hipStream_t stream) {
  const float* x    = (const float*)d_in[0];
  const float* W    = (const float*)d_in[1];
  const float* bias = (const float*)d_in[2];
  float* out = (float*)d_out;

  // ws: xb | xTb | Wt | Wts | vTb (bf16) | barrier words  (~15.3 MB)
  bf16_t* xb  = (bf16_t*)d_ws;
  bf16_t* xTb = xb  + (size_t)CB * CK;
  bf16_t* Wt  = xTb + (size_t)CB * CK;
  bf16_t* Wts = Wt  + (size_t)NCO * CK;
  bf16_t* vTb = Wts + (size_t)NCO * CK;
  unsigned* bar = (unsigned*)(vTb + (size_t)NCO * CB);

  hipMemsetAsync(bar, 0, 8, stream);   // cnt=0, gen=0 (poison-safe, capture-legal)

  void* args[] = {(void*)&x, (void*)&W, (void*)&bias, (void*)&out,
                  (void*)&xb, (void*)&xTb, (void*)&Wt, (void*)&Wts,
                  (void*)&vTb, (void*)&bar};
  hipLaunchCooperativeKernel((const void*)k_fused, dim3(GRD), dim3(THR),
                             args, 0, stream);
}

// Round 8
// 184.524 us; speedup vs baseline: 1.1251x; 1.1251x over previous
//
#include <hip/hip_runtime.h>

#define CB 256   // batch
#define CR 1152  // routes
#define CC 10    // class capsules
#define CO 16    // out dim
#define CI 8     // in dim
#define CK (CR*CI)   // 9216
#define NCO (CC*CO)  // 160
#define GRD 160
#define THR 512

typedef __bf16 bf16_t;
typedef __attribute__((ext_vector_type(8))) __bf16 bf16x8;
typedef __attribute__((ext_vector_type(4))) float f32x4;

union SMem {
  float Ls[8][64][4];                 // s-phase partials (8 KB)
  unsigned short vL[NCO][CB + 8];     // asc-phase v staging (84.5 KB)
};

// grid barrier, load-poll flavor: one RMW per block to arrive; pollers issue
// read-only agent-scope loads (no ownership transfer) with s_sleep backoff.
// gen increases monotonically per barrier; caller passes expected value, so a
// stale (older) poll value can never cause early exit. cnt/gen zeroed by
// hipMemsetAsync before each launch.
__device__ __forceinline__ void gbar(unsigned* cnt, unsigned* gen, unsigned expect) {
  __syncthreads();
  if (threadIdx.x == 0) {
    __threadfence();                          // release this phase's writes
    const unsigned old = atomicAdd(cnt, 1u);  // arrive (device scope)
    if (old == GRD - 1) {
      atomicExch(cnt, 0u);                    // reset for next use
      __threadfence();                        // order reset before release
      atomicAdd(gen, 1u);                     // release everyone
    } else {
      while (__hip_atomic_load(gen, __ATOMIC_RELAXED, __HIP_MEMORY_SCOPE_AGENT) < expect)
        __builtin_amdgcn_s_sleep(8);
    }
    __threadfence();                          // acquire remote writes
  }
  __syncthreads();
}

__global__ __launch_bounds__(THR, 1) void k_fused(
    const float* __restrict__ x, const float* __restrict__ W,
    const float* __restrict__ bias, float* __restrict__ out,
    bf16_t* __restrict__ xb, bf16_t* __restrict__ xTb,
    bf16_t* __restrict__ Wt, bf16_t* __restrict__ Wts,
    bf16_t* __restrict__ vTb, unsigned* __restrict__ bar) {
  __shared__ SMem sm;
  __shared__ float bL[8][CC];     // persistent routing logits (this block's 8 r's)
  __shared__ float agrL[8][CC];
  __shared__ float cwL[8][CC];

  const int blk = blockIdx.x;
  const int t = threadIdx.x;
  const int tid = blk * THR + t;  // 81920 threads
  unsigned nbar = 0;              // barrier generation tracker (uniform across block)

  // ---------------- phase 0: cvt  x->xb [b][k], x->xTb [k][b], W->Wt [co][k] ----------------
  for (int vi = tid; vi < CB * CK / 8; vi += GRD * THR) {
    const float4 f0 = ((const float4*)x)[vi * 2];
    const float4 f1 = ((const float4*)x)[vi * 2 + 1];
    bf16x8 ov;
    ov[0] = (bf16_t)f0.x; ov[1] = (bf16_t)f0.y; ov[2] = (bf16_t)f0.z; ov[3] = (bf16_t)f0.w;
    ov[4] = (bf16_t)f1.x; ov[5] = (bf16_t)f1.y; ov[6] = (bf16_t)f1.z; ov[7] = (bf16_t)f1.w;
    ((bf16x8*)xb)[vi] = ov;
  }
  for (int u = tid; u < CK * (CB / 8); u += GRD * THR) {
    const int k = u % CK, bg = u / CK, b0 = bg * 8;
    bf16x8 tv;
    #pragma unroll
    for (int j = 0; j < 8; ++j) tv[j] = (bf16_t)x[(size_t)(b0 + j) * CK + k];
    *(bf16x8*)(xTb + (size_t)k * CB + b0) = tv;
  }
  for (int wi = tid; wi < NCO * CR; wi += GRD * THR) {
    const int r = wi % CR;
    const int co = wi / CR;
    const int c = co >> 4, o = co & 15;
    const float4* src = (const float4*)(W + (((size_t)r * CC + c) * CO + o) * CI);
    const float4 f0 = src[0], f1 = src[1];
    bf16x8 v;
    v[0] = (bf16_t)f0.x; v[1] = (bf16_t)f0.y; v[2] = (bf16_t)f0.z; v[3] = (bf16_t)f0.w;
    v[4] = (bf16_t)f1.x; v[5] = (bf16_t)f1.y; v[6] = (bf16_t)f1.z; v[7] = (bf16_t)f1.w;
    *(bf16x8*)(Wt + (size_t)co * CK + r * 8) = v;
  }
  gbar(bar, bar + 1, ++nbar);

  for (int it = 0; it < 3; ++it) {
    // ---------------- s + squash: 160 blocks = (bt,c), 8 waves split K ----------------
    {
      const int xcd = blk & 7, j = blk >> 3;
      const int bt = xcd * 2 + (j & 1);
      const int c = j >> 1;
      const int w = t >> 6, lane = t & 63;
      const int mrow = lane & 15, kg = lane >> 4;
      const int b0 = bt * 16;
      const bf16_t* __restrict__ Bmat = (it == 0) ? Wt : Wts;
      const size_t kbase = (size_t)w * (CK / 8);
      const bf16x8* ap = (const bf16x8*)(xb + (size_t)(b0 + mrow) * CK + kbase) + kg;
      const bf16x8* bp = (const bf16x8*)(Bmat + (size_t)(c * CO + mrow) * CK + kbase) + kg;
      f32x4 acc0 = {0.f, 0.f, 0.f, 0.f}, acc1 = {0.f, 0.f, 0.f, 0.f};
      #pragma unroll 6
      for (int s = 0; s < 36; s += 2) {
        acc0 = __builtin_amdgcn_mfma_f32_16x16x32_bf16(ap[s * 4], bp[s * 4], acc0, 0, 0, 0);
        acc1 = __builtin_amdgcn_mfma_f32_16x16x32_bf16(ap[(s + 1) * 4], bp[(s + 1) * 4], acc1, 0, 0, 0);
      }
      const f32x4 acc = acc0 + acc1;
      #pragma unroll
      for (int reg = 0; reg < 4; ++reg) sm.Ls[w][lane][reg] = acc[reg];
      __syncthreads();
      if (t < 256) {
        const int row = t >> 4, col = t & 15;
        const int l = ((row >> 2) << 4) | col, reg = row & 3;
        float s = 0.f;
        #pragma unroll
        for (int q = 0; q < 8; ++q) s += sm.Ls[q][l][reg];
        if (it == 0) s *= 0.1f;          // uniform c_ij = 1/10
        s += bias[c * CO + col];
        float n2 = s * s;
        #pragma unroll
        for (int m = 1; m < 16; m <<= 1) n2 += __shfl_xor(n2, m);
        const float vv = s * n2 / (1.f + n2) * rsqrtf(n2 + 1e-8f);
        if (it == 2) out[(size_t)(b0 + row) * NCO + c * CO + col] = vv;
        else         vTb[(size_t)(c * CO + col) * CB + b0 + row] = (bf16_t)vv;
      }
    }
    if (it == 2) break;
    gbar(bar, bar + 1, ++nbar);

    // ---------------- agree + softmax + prescale: blocks 0..143, class-halves ----------------
    if (blk < 144) {
      const int r0 = blk * 8;
      const int h = t >> 8;
      const int th = t & 255;
      const int w = th >> 6, lane = th & 63;
      const int mrow = lane & 15, kg = lane >> 4;

      #pragma unroll
      for (int q = 0; q < 10; ++q) {     // stage vTb (5120 bf16x8) into LDS
        const int idx = q * THR + t;
        const int co = idx >> 5, bs = idx & 31;
        const bf16x8 v = ((const bf16x8*)vTb)[idx];
        *(bf16x8*)&sm.vL[co][bs * 8] = v;
      }
      const int m0 = r0 * 8 + w * 16;    // A rows (r,i), K = b = 256
      const bf16x8* ap = (const bf16x8*)(xTb + (size_t)(m0 + mrow) * CB) + kg;
      bf16x8 a[8];
      #pragma unroll
      for (int s = 0; s < 8; ++s) a[s] = ap[s * 4];
      __syncthreads();

      const int o = lane & 15, g = lane >> 4;
      #pragma unroll
      for (int cc = 0; cc < 5; ++cc) {
        const int c = h * 5 + cc;
        f32x4 acc = {0.f, 0.f, 0.f, 0.f};
        #pragma unroll
        for (int s = 0; s < 8; ++s) {
          const bf16x8 bv = *(const bf16x8*)&sm.vL[c * CO + mrow][s * 32 + kg * 8];
          acc = __builtin_amdgcn_mfma_f32_16x16x32_bf16(a[s], bv, acc, 0, 0, 0);
        }
        float p = 0.f;
        #pragma unroll
        for (int reg = 0; reg < 4; ++reg) {
          const int m = g * 4 + reg, rl = m >> 3, i = m & 7;
          p += acc[reg] * W[(((size_t)(r0 + w * 2 + rl) * CC + c) * CO + o) * CI + i];
        }
        #pragma unroll
        for (int msk = 1; msk < 32; msk <<= 1) p += __shfl_xor(p, msk);
        if ((lane & 31) == 0) agrL[w * 2 + (lane >> 5)][c] = p * (1.0f / CB);
      }
      __syncthreads();

      if (t < 8) {
        float nb[CC];
        float mx = -1e30f;
        #pragma unroll
        for (int c = 0; c < CC; ++c) {
          nb[c] = (it == 0 ? 0.f : bL[t][c]) + agrL[t][c];
          mx = fmaxf(mx, nb[c]);
        }
        float sum = 0.f;
        #pragma unroll
        for (int c = 0; c < CC; ++c) {
          bL[t][c] = nb[c];
          const float e = __expf(nb[c] - mx);
          cwL[t][c] = e;
          sum += e;
        }
        const float inv = 1.f / sum;
        #pragma unroll
        for (int c = 0; c < CC; ++c) cwL[t][c] *= inv;
      }
      __syncthreads();

      #pragma unroll
      for (int q = 0; q < 3; ++q) {      // Wts = Wt * c_ij for this block's 8 r's
        const int slot = q * THR + t;
        if (slot < 1280) {
          const int co = slot >> 3, rl = slot & 7;
          const float cw = cwL[rl][co >> 4];
          const size_t off = (size_t)co * CK + (r0 + rl) * 8;
          const bf16x8 wv = *(const bf16x8*)(Wt + off);
          bf16x8 ov;
          #pragma unroll
          for (int jj = 0; jj < 8; ++jj) ov[jj] = (bf16_t)((float)wv[jj] * cw);
          *(bf16x8*)(Wts + off) = ov;
        }
      }
    }
    gbar(bar, bar + 1, ++nbar);
  }
}

extern "C" void kernel_launch(void* const* d_in, const int* in_sizes, int n_in,
                              void* d_out, int out_size, void* d_ws, size_t ws_size,
                              hipStream_t stream) {
  const float* x    = (const float*)d_in[0];
  const float* W    = (const float*)d_in[1];
  const float* bias = (const float*)d_in[2];
  float* out = (float*)d_out;

  // ws: xb | xTb | Wt | Wts | vTb (bf16) | barrier words  (~15.3 MB)
  bf16_t* xb  = (bf16_t*)d_ws;
  bf16_t* xTb = xb  + (size_t)CB * CK;
  bf16_t* Wt  = xTb + (size_t)CB * CK;
  bf16_t* Wts = Wt  + (size_t)NCO * CK;
  bf16_t* vTb = Wts + (size_t)NCO * CK;
  unsigned* bar = (unsigned*)(vTb + (size_t)NCO * CB);

  hipMemsetAsync(bar, 0, 8, stream);   // cnt=0, gen=0 (poison-safe, capture-legal)

  void* args[] = {(void*)&x, (void*)&W, (void*)&bias, (void*)&out,
                  (void*)&xb, (void*)&xTb, (void*)&Wt, (void*)&Wts,
                  (void*)&vTb, (void*)&bar};
  hipLaunchCooperativeKernel((const void*)k_fused, dim3(GRD), dim3(THR),
                             args, 0, stream);
}

// Round 9
// 165.391 us; speedup vs baseline: 1.2552x; 1.1157x over previous
//
#include <hip/hip_runtime.h>

#define CB 256   // batch
#define CR 1152  // routes
#define CC 10    // class capsules
#define CO 16    // out dim
#define CI 8     // in dim
#define CK (CR*CI)   // 9216
#define NCO (CC*CO)  // 160
#define GRD 160
#define THR 512

typedef __bf16 bf16_t;
typedef unsigned long long u64;
typedef __attribute__((ext_vector_type(8))) __bf16 bf16x8;
typedef __attribute__((ext_vector_type(4))) float f32x4;

union SMem {
  float Ls[8][64][4];                 // s-phase partials (8 KB)
  unsigned short vL[NCO][CB + 8];     // asc-phase v staging (84.5 KB)
};

// ---- agent-scope (cross-XCD coherent, L2-bypassing) access helpers ----
__device__ __forceinline__ void store8_agent(bf16_t* p, bf16x8 v) {
  union { bf16x8 v; u64 q[2]; } u; u.v = v;
  u64* q = (u64*)p;
  __hip_atomic_store(q,     u.q[0], __ATOMIC_RELAXED, __HIP_MEMORY_SCOPE_AGENT);
  __hip_atomic_store(q + 1, u.q[1], __ATOMIC_RELAXED, __HIP_MEMORY_SCOPE_AGENT);
}
__device__ __forceinline__ bf16x8 load8_agent(const bf16_t* p) {
  union { bf16x8 v; u64 q[2]; } u;
  const u64* q = (const u64*)p;
  u.q[0] = __hip_atomic_load(q,     __ATOMIC_RELAXED, __HIP_MEMORY_SCOPE_AGENT);
  u.q[1] = __hip_atomic_load(q + 1, __ATOMIC_RELAXED, __HIP_MEMORY_SCOPE_AGENT);
  return u.v;
}
__device__ __forceinline__ void store2_agent(bf16_t* p, float f) {
  union { __bf16 h; unsigned short s; } u; u.h = (bf16_t)f;
  __hip_atomic_store((unsigned short*)p, u.s, __ATOMIC_RELAXED, __HIP_MEMORY_SCOPE_AGENT);
}

// ---- lite grid barrier: no cache maintenance. Monotone count, no reset.
// Producers drain their (write-through) stores with vmcnt(0) before arriving,
// so poll-success implies all agent data is at the LLC. Mutable cross-phase
// data is agent-accessed only -> no buffer_inv needed on the consumer side.
__device__ __forceinline__ void gbar_lite(unsigned* cnt, unsigned* gen, unsigned nbar) {
  __syncthreads();
  if (threadIdx.x == 0) {
    asm volatile("s_waitcnt vmcnt(0)" ::: "memory");
    const unsigned old = __hip_atomic_fetch_add(cnt, 1u, __ATOMIC_RELAXED, __HIP_MEMORY_SCOPE_AGENT);
    if (old == nbar * GRD - 1) {
      __hip_atomic_store(gen, nbar, __ATOMIC_RELAXED, __HIP_MEMORY_SCOPE_AGENT);
    } else {
      while (__hip_atomic_load(gen, __ATOMIC_RELAXED, __HIP_MEMORY_SCOPE_AGENT) < nbar)
        __builtin_amdgcn_s_sleep(8);
    }
  }
  __syncthreads();
}

__global__ __launch_bounds__(THR, 1) void k_fused(
    const float* __restrict__ x, const float* __restrict__ W,
    const float* __restrict__ bias, float* __restrict__ out,
    bf16_t* __restrict__ xb, bf16_t* __restrict__ xTb,
    bf16_t* __restrict__ Wt, bf16_t* __restrict__ Wts,
    bf16_t* __restrict__ vTb, unsigned* __restrict__ bar) {
  __shared__ SMem sm;
  __shared__ float bL[8][CC];     // persistent routing logits (this block's 8 r's)
  __shared__ float agrL[8][CC];
  __shared__ float cwL[8][CC];

  const int blk = blockIdx.x;
  const int t = threadIdx.x;
  const int tid = blk * THR + t;  // 81920 threads
  unsigned nbar = 0;

  // ---------------- phase 0: cvt  x->xb [b][k], x->xTb [k][b], W->Wt [co][k] ----------------
  // All products are replay-invariant; written write-through (agent) so later
  // normal cached reads are always coherent (stale lines == identical bytes).
  for (int vi = tid; vi < CB * CK / 8; vi += GRD * THR) {
    const float4 f0 = ((const float4*)x)[vi * 2];
    const float4 f1 = ((const float4*)x)[vi * 2 + 1];
    bf16x8 ov;
    ov[0] = (bf16_t)f0.x; ov[1] = (bf16_t)f0.y; ov[2] = (bf16_t)f0.z; ov[3] = (bf16_t)f0.w;
    ov[4] = (bf16_t)f1.x; ov[5] = (bf16_t)f1.y; ov[6] = (bf16_t)f1.z; ov[7] = (bf16_t)f1.w;
    store8_agent(xb + (size_t)vi * 8, ov);
  }
  for (int u = tid; u < CK * (CB / 8); u += GRD * THR) {
    const int k = u % CK, bg = u / CK, b0 = bg * 8;
    bf16x8 tv;
    #pragma unroll
    for (int j = 0; j < 8; ++j) tv[j] = (bf16_t)x[(size_t)(b0 + j) * CK + k];
    store8_agent(xTb + (size_t)k * CB + b0, tv);
  }
  for (int wi = tid; wi < NCO * CR; wi += GRD * THR) {
    const int r = wi % CR;
    const int co = wi / CR;
    const int c = co >> 4, o = co & 15;
    const float4* src = (const float4*)(W + (((size_t)r * CC + c) * CO + o) * CI);
    const float4 f0 = src[0], f1 = src[1];
    bf16x8 v;
    v[0] = (bf16_t)f0.x; v[1] = (bf16_t)f0.y; v[2] = (bf16_t)f0.z; v[3] = (bf16_t)f0.w;
    v[4] = (bf16_t)f1.x; v[5] = (bf16_t)f1.y; v[6] = (bf16_t)f1.z; v[7] = (bf16_t)f1.w;
    store8_agent(Wt + (size_t)co * CK + r * 8, v);
  }
  gbar_lite(bar, bar + 1, ++nbar);

  for (int it = 0; it < 3; ++it) {
    // ---------------- s + squash: 160 blocks = (bt,c), 8 waves split K ----------------
    {
      const int xcd = blk & 7, j = blk >> 3;
      const int bt = xcd * 2 + (j & 1);
      const int c = j >> 1;
      const int w = t >> 6, lane = t & 63;
      const int mrow = lane & 15, kg = lane >> 4;
      const int b0 = bt * 16;
      const size_t kbase = (size_t)w * (CK / 8);
      const bf16x8* ap = (const bf16x8*)(xb + (size_t)(b0 + mrow) * CK + kbase) + kg;
      f32x4 acc0 = {0.f, 0.f, 0.f, 0.f}, acc1 = {0.f, 0.f, 0.f, 0.f};
      if (it == 0) {
        // B = Wt: read-only after phase 0 -> normal cached loads
        const bf16x8* bp = (const bf16x8*)(Wt + (size_t)(c * CO + mrow) * CK + kbase) + kg;
        #pragma unroll 6
        for (int s = 0; s < 36; s += 2) {
          acc0 = __builtin_amdgcn_mfma_f32_16x16x32_bf16(ap[s * 4], bp[s * 4], acc0, 0, 0, 0);
          acc1 = __builtin_amdgcn_mfma_f32_16x16x32_bf16(ap[(s + 1) * 4], bp[(s + 1) * 4], acc1, 0, 0, 0);
        }
      } else {
        // B = Wts: mutable across phases -> agent loads (coherent, uncached)
        const bf16_t* bbase = Wts + (size_t)(c * CO + mrow) * CK + kbase + kg * 8;
        #pragma unroll 6
        for (int s = 0; s < 36; s += 2) {
          const bf16x8 b0v = load8_agent(bbase + (size_t)s * 32);
          const bf16x8 b1v = load8_agent(bbase + (size_t)(s + 1) * 32);
          acc0 = __builtin_amdgcn_mfma_f32_16x16x32_bf16(ap[s * 4], b0v, acc0, 0, 0, 0);
          acc1 = __builtin_amdgcn_mfma_f32_16x16x32_bf16(ap[(s + 1) * 4], b1v, acc1, 0, 0, 0);
        }
      }
      const f32x4 acc = acc0 + acc1;
      #pragma unroll
      for (int reg = 0; reg < 4; ++reg) sm.Ls[w][lane][reg] = acc[reg];
      __syncthreads();
      if (t < 256) {
        const int row = t >> 4, col = t & 15;
        const int l = ((row >> 2) << 4) | col, reg = row & 3;
        float s = 0.f;
        #pragma unroll
        for (int q = 0; q < 8; ++q) s += sm.Ls[q][l][reg];
        if (it == 0) s *= 0.1f;          // uniform c_ij = 1/10
        s += bias[c * CO + col];
        float n2 = s * s;
        #pragma unroll
        for (int m = 1; m < 16; m <<= 1) n2 += __shfl_xor(n2, m);
        const float vv = s * n2 / (1.f + n2) * rsqrtf(n2 + 1e-8f);
        if (it == 2) out[(size_t)(b0 + row) * NCO + c * CO + col] = vv;
        else         store2_agent(vTb + (size_t)(c * CO + col) * CB + b0 + row, vv);
      }
    }
    if (it == 2) break;
    gbar_lite(bar, bar + 1, ++nbar);

    // ---------------- agree + softmax + prescale: blocks 0..143, class-halves ----------------
    if (blk < 144) {
      const int r0 = blk * 8;
      const int h = t >> 8;
      const int th = t & 255;
      const int w = th >> 6, lane = th & 63;
      const int mrow = lane & 15, kg = lane >> 4;

      #pragma unroll
      for (int q = 0; q < 10; ++q) {     // stage vTb (5120 bf16x8) into LDS
        const int idx = q * THR + t;
        const int co = idx >> 5, bs = idx & 31;
        const bf16x8 v = load8_agent(vTb + (size_t)idx * 8);
        *(bf16x8*)&sm.vL[co][bs * 8] = v;
      }
      const int m0 = r0 * 8 + w * 16;    // A rows (r,i), K = b = 256
      const bf16x8* ap = (const bf16x8*)(xTb + (size_t)(m0 + mrow) * CB) + kg;
      bf16x8 a[8];
      #pragma unroll
      for (int s = 0; s < 8; ++s) a[s] = ap[s * 4];
      __syncthreads();

      const int o = lane & 15, g = lane >> 4;
      #pragma unroll
      for (int cc = 0; cc < 5; ++cc) {
        const int c = h * 5 + cc;
        f32x4 acc = {0.f, 0.f, 0.f, 0.f};
        #pragma unroll
        for (int s = 0; s < 8; ++s) {
          const bf16x8 bv = *(const bf16x8*)&sm.vL[c * CO + mrow][s * 32 + kg * 8];
          acc = __builtin_amdgcn_mfma_f32_16x16x32_bf16(a[s], bv, acc, 0, 0, 0);
        }
        float p = 0.f;
        #pragma unroll
        for (int reg = 0; reg < 4; ++reg) {
          const int m = g * 4 + reg, rl = m >> 3, i = m & 7;
          p += acc[reg] * W[(((size_t)(r0 + w * 2 + rl) * CC + c) * CO + o) * CI + i];
        }
        #pragma unroll
        for (int msk = 1; msk < 32; msk <<= 1) p += __shfl_xor(p, msk);
        if ((lane & 31) == 0) agrL[w * 2 + (lane >> 5)][c] = p * (1.0f / CB);
      }
      __syncthreads();

      if (t < 8) {
        float nb[CC];
        float mx = -1e30f;
        #pragma unroll
        for (int c = 0; c < CC; ++c) {
          nb[c] = (it == 0 ? 0.f : bL[t][c]) + agrL[t][c];
          mx = fmaxf(mx, nb[c]);
        }
        float sum = 0.f;
        #pragma unroll
        for (int c = 0; c < CC; ++c) {
          bL[t][c] = nb[c];
          const float e = __expf(nb[c] - mx);
          cwL[t][c] = e;
          sum += e;
        }
        const float inv = 1.f / sum;
        #pragma unroll
        for (int c = 0; c < CC; ++c) cwL[t][c] *= inv;
      }
      __syncthreads();

      #pragma unroll
      for (int q = 0; q < 3; ++q) {      // Wts = Wt * c_ij for this block's 8 r's
        const int slot = q * THR + t;
        if (slot < 1280) {
          const int co = slot >> 3, rl = slot & 7;
          const float cw = cwL[rl][co >> 4];
          const size_t off = (size_t)co * CK + (r0 + rl) * 8;
          const bf16x8 wv = *(const bf16x8*)(Wt + off);   // read-only -> cached
          bf16x8 ov;
          #pragma unroll
          for (int jj = 0; jj < 8; ++jj) ov[jj] = (bf16_t)((float)wv[jj] * cw);
          store8_agent(Wts + off, ov);
        }
      }
    }
    gbar_lite(bar, bar + 1, ++nbar);
  }
}

extern "C" void kernel_launch(void* const* d_in, const int* in_sizes, int n_in,
                              void* d_out, int out_size, void* d_ws, size_t ws_size,
                              hipStream_t stream) {
  const float* x    = (const float*)d_in[0];
  const float* W    = (const float*)d_in[1];
  const float* bias = (const float*)d_in[2];
  float* out = (float*)d_out;

  // ws: xb | xTb | Wt | Wts | vTb (bf16) | barrier words  (~15.3 MB)
  bf16_t* xb  = (bf16_t*)d_ws;
  bf16_t* xTb = xb  + (size_t)CB * CK;
  bf16_t* Wt  = xTb + (size_t)CB * CK;
  bf16_t* Wts = Wt  + (size_t)NCO * CK;
  bf16_t* vTb = Wts + (size_t)NCO * CK;
  unsigned* bar = (unsigned*)(vTb + (size_t)NCO * CB);

  hipMemsetAsync(bar, 0, 8, stream);   // cnt=0, gen=0 (capture-legal)

  void* args[] = {(void*)&x, (void*)&W, (void*)&bias, (void*)&out,
                  (void*)&xb, (void*)&xTb, (void*)&Wt, (void*)&Wts,
                  (void*)&vTb, (void*)&bar};
  hipLaunchCooperativeKernel((const void*)k_fused, dim3(GRD), dim3(THR),
                             args, 0, stream);
}

// Round 10
// 103.851 us; speedup vs baseline: 1.9990x; 1.5926x over previous
//
#include <hip/hip_runtime.h>

#define CB 256   // batch
#define CR 1152  // routes
#define CC 10    // class capsules
#define CO 16    // out dim
#define CI 8     // in dim
#define CK (CR*CI)   // 9216
#define NCO (CC*CO)  // 160

typedef __bf16 bf16_t;
typedef __attribute__((ext_vector_type(8))) __bf16 bf16x8;
typedef __attribute__((ext_vector_type(4))) float f32x4;

__device__ __forceinline__ unsigned short bfbits(float f) {
  union { __bf16 h; unsigned short u; } u; u.h = (bf16_t)f; return u.u;
}

// ---------------- fused s + squash, inline fp32->bf16 convert ----------------
// grid 160 = (16 bt, 10 c) XCD-grouped, block 512 = 8 waves splitting K=9216.
// s[b,c,o] = sum_r cw[r,c] * (W[r,c,o,:] . x[b,r,:]) ; MODE0: cw = 1/10 post-scale.
template<int MODE, bool LAST>
__global__ __launch_bounds__(512) void k_s(const float* __restrict__ x,
                                           const float* __restrict__ W,
                                           const float* __restrict__ bias,
                                           const float* __restrict__ cwT,
                                           bf16_t* __restrict__ vTb,
                                           float* __restrict__ out) {
  const int blk = blockIdx.x;
  // 4bt x 5c per XCD: per-XCD L2 set = 4 x-slices (2.3MB) + 5 W c-slices (2.95MB)
  const int xcd = blk & 7, j = blk >> 3;
  const int bt = (xcd & 3) * 4 + (j & 3);
  const int c  = (xcd >> 2) * 5 + (j >> 2);
  const int t = threadIdx.x;
  const int w = t >> 6, lane = t & 63;
  const int mrow = lane & 15, kg = lane >> 4;
  const int b0 = bt * 16;

  __shared__ float cwS[CR];
  __shared__ float Ls[8][64][4];
  if (MODE == 1) {
    if (t < CR / 4) ((float4*)cwS)[t] = ((const float4*)(cwT + (size_t)c * CR))[t];
    __syncthreads();
  }

  // A rows = b (x fp32, contiguous 8 floats); B rows = o (W fp32, one r per frag)
  const int r0w = w * 144;                       // this wave's first r
  const float4* ax = (const float4*)(x + (size_t)(b0 + mrow) * CK + (size_t)w * 1152) + kg * 2;

  f32x4 acc = {0.f, 0.f, 0.f, 0.f};
  #pragma unroll 4
  for (int s = 0; s < 36; ++s) {
    const float4 a0 = ax[s * 8], a1 = ax[s * 8 + 1];
    const int r = r0w + s * 4 + kg;
    const float4* wp = (const float4*)(W + (((size_t)r * CC + c) * CO + mrow) * CI);
    const float4 w0 = wp[0], w1 = wp[1];
    bf16x8 af, bf;
    af[0] = (bf16_t)a0.x; af[1] = (bf16_t)a0.y; af[2] = (bf16_t)a0.z; af[3] = (bf16_t)a0.w;
    af[4] = (bf16_t)a1.x; af[5] = (bf16_t)a1.y; af[6] = (bf16_t)a1.z; af[7] = (bf16_t)a1.w;
    if (MODE == 1) {
      const float cw = cwS[r];
      bf[0] = (bf16_t)(w0.x * cw); bf[1] = (bf16_t)(w0.y * cw);
      bf[2] = (bf16_t)(w0.z * cw); bf[3] = (bf16_t)(w0.w * cw);
      bf[4] = (bf16_t)(w1.x * cw); bf[5] = (bf16_t)(w1.y * cw);
      bf[6] = (bf16_t)(w1.z * cw); bf[7] = (bf16_t)(w1.w * cw);
    } else {
      bf[0] = (bf16_t)w0.x; bf[1] = (bf16_t)w0.y; bf[2] = (bf16_t)w0.z; bf[3] = (bf16_t)w0.w;
      bf[4] = (bf16_t)w1.x; bf[5] = (bf16_t)w1.y; bf[6] = (bf16_t)w1.z; bf[7] = (bf16_t)w1.w;
    }
    acc = __builtin_amdgcn_mfma_f32_16x16x32_bf16(af, bf, acc, 0, 0, 0);
  }

  #pragma unroll
  for (int reg = 0; reg < 4; ++reg) Ls[w][lane][reg] = acc[reg];
  __syncthreads();

  if (t < 256) {
    const int row = t >> 4, col = t & 15;          // row = b-local, col = o
    const int l = ((row >> 2) << 4) | col, reg = row & 3;
    float s = 0.f;
    #pragma unroll
    for (int q = 0; q < 8; ++q) s += Ls[q][l][reg];
    if (MODE == 0) s *= 0.1f;                      // uniform c_ij = 1/10
    s += bias[c * CO + col];
    float n2 = s * s;
    #pragma unroll
    for (int m = 1; m < 16; m <<= 1) n2 += __shfl_xor(n2, m);
    const float vv = s * n2 / (1.f + n2) * rsqrtf(n2 + 1e-8f);
    if (LAST) out[(size_t)(b0 + row) * NCO + c * CO + col] = vv;
    else      vTb[(size_t)(c * CO + col) * CB + b0 + row] = (bf16_t)vv;
  }
}

// ---------------- agree + softmax -> cwT: 144 blocks x 512 thr (class-halves) ----------------
// G[(r,i),(c,o)] = sum_b x[b,(r,i)] * v[b,(c,o)] via MFMA (K=256);
// agree[r,c] = (1/B) sum_{i,o} W*G ; b_ij (+)= agree ; cwT[c][r] = softmax_c(b_ij)
template<bool FIRST>
__global__ __launch_bounds__(512) void k_asc(const float* __restrict__ x,
                                             const float* __restrict__ W,
                                             const bf16_t* __restrict__ vTb,
                                             float* __restrict__ b_ij,
                                             float* __restrict__ cwT) {
  const int r0 = blockIdx.x * 8;
  const int t = threadIdx.x;
  const int h = t >> 8;            // class-half 0/1
  const int th = t & 255;
  const int w = th >> 6, lane = th & 63;
  const int mrow = lane & 15, kg = lane >> 4;

  __shared__ __align__(16) unsigned short vL[NCO][CB + 8];   // 84.5 KB
  __shared__ __align__(16) unsigned short xTl[64][CB + 8];   // 33.8 KB
  __shared__ float agrL[8][CC];
  __shared__ float cwL[8][CC];

  // stage vTb (5120 bf16x8) into LDS
  #pragma unroll
  for (int q = 0; q < 10; ++q) {
    const int idx = q * 512 + t;
    const int co = idx >> 5, bs = idx & 31;
    const bf16x8 v = ((const bf16x8*)vTb)[idx];
    *(bf16x8*)&vL[co][bs * 8] = v;
  }
  // stage x-slice transposed: xTl[ri][b] = bf16(x[b][r0*8+ri])
  #pragma unroll
  for (int chunk = 0; chunk < 16; ++chunk) {
    const int b = chunk * 16 + (t >> 5);
    const int ri = (t & 31) * 2;
    const float2 v = *(const float2*)(x + (size_t)b * CK + r0 * 8 + ri);
    xTl[ri][b] = bfbits(v.x);
    xTl[ri + 1][b] = bfbits(v.y);
  }
  __syncthreads();

  // A fragments from LDS: rows (r,i) local = w*16+mrow, K = b
  bf16x8 a[8];
  #pragma unroll
  for (int s = 0; s < 8; ++s)
    a[s] = *(const bf16x8*)&xTl[w * 16 + mrow][s * 32 + kg * 8];

  const int o = lane & 15, g = lane >> 4;
  #pragma unroll
  for (int cc = 0; cc < 5; ++cc) {
    const int c = h * 5 + cc;
    f32x4 acc = {0.f, 0.f, 0.f, 0.f};
    #pragma unroll
    for (int s = 0; s < 8; ++s) {
      const bf16x8 bv = *(const bf16x8*)&vL[c * CO + mrow][s * 32 + kg * 8];
      acc = __builtin_amdgcn_mfma_f32_16x16x32_bf16(a[s], bv, acc, 0, 0, 0);
    }
    float p = 0.f;
    #pragma unroll
    for (int reg = 0; reg < 4; ++reg) {
      const int m = g * 4 + reg, rl = m >> 3, i = m & 7;
      p += acc[reg] * W[(((size_t)(r0 + w * 2 + rl) * CC + c) * CO + o) * CI + i];
    }
    #pragma unroll
    for (int msk = 1; msk < 32; msk <<= 1) p += __shfl_xor(p, msk);
    if ((lane & 31) == 0) agrL[w * 2 + (lane >> 5)][c] = p * (1.0f / CB);
  }
  __syncthreads();

  if (t < 8) {
    const int r = r0 + t;
    float nb[CC];
    float mx = -1e30f;
    #pragma unroll
    for (int c = 0; c < CC; ++c) {
      nb[c] = (FIRST ? 0.f : b_ij[r * CC + c]) + agrL[t][c];
      mx = fmaxf(mx, nb[c]);
    }
    float sum = 0.f;
    #pragma unroll
    for (int c = 0; c < CC; ++c) {
      b_ij[r * CC + c] = nb[c];
      const float e = __expf(nb[c] - mx);
      cwL[t][c] = e;
      sum += e;
    }
    const float inv = 1.f / sum;
    #pragma unroll
    for (int c = 0; c < CC; ++c) cwT[(size_t)c * CR + r] = cwL[t][c] * inv;
  }
}

extern "C" void kernel_launch(void* const* d_in, const int* in_sizes, int n_in,
                              void* d_out, int out_size, void* d_ws, size_t ws_size,
                              hipStream_t stream) {
  const float* x    = (const float*)d_in[0];
  const float* W    = (const float*)d_in[1];
  const float* bias = (const float*)d_in[2];
  float* out = (float*)d_out;

  // ws: vTb bf16 [NCO][CB] | b_ij f32 [R][C] | cwT f32 [C][R]   (~172 KB)
  bf16_t* vTb  = (bf16_t*)d_ws;
  float*  b_ij = (float*)(vTb + (size_t)NCO * CB);
  float*  cwT  = b_ij + (size_t)CR * CC;

  // iter 0 (uniform c_ij)
  k_s<0, false><<<160, 512, 0, stream>>>(x, W, bias, cwT, vTb, out);
  k_asc<true><<<144, 512, 0, stream>>>(x, W, vTb, b_ij, cwT);

  // iter 1
  k_s<1, false><<<160, 512, 0, stream>>>(x, W, bias, cwT, vTb, out);
  k_asc<false><<<144, 512, 0, stream>>>(x, W, vTb, b_ij, cwT);

  // iter 2 (final -> out)
  k_s<1, true><<<160, 512, 0, stream>>>(x, W, bias, cwT, vTb, out);
}

// Round 11
// 97.487 us; speedup vs baseline: 2.1295x; 1.0653x over previous
//
#include <hip/hip_runtime.h>

#define CB 256   // batch
#define CR 1152  // routes
#define CC 10    // class capsules
#define CO 16    // out dim
#define CI 8     // in dim
#define CK (CR*CI)   // 9216
#define NCO (CC*CO)  // 160

typedef __bf16 bf16_t;
typedef __attribute__((ext_vector_type(8))) __bf16 bf16x8;
typedef __attribute__((ext_vector_type(4))) float f32x4;

__device__ __forceinline__ unsigned short bfbits(float f) {
  union { __bf16 h; unsigned short u; } u; u.h = (bf16_t)f; return u.u;
}

// ---------------- s0: fused cvt + s + squash (iteration 0, uniform c_ij) ----------------
// 160 blocks = (16 bt, 10 c), 1024 thr = 16 waves splitting K=9216 (18 MFMA steps each).
// Reads fp32 x/W, converts inline; c==0 blocks side-write xb, bt==0 blocks side-write Wt.
__global__ __launch_bounds__(1024) void k_s0(const float* __restrict__ x,
                                             const float* __restrict__ W,
                                             const float* __restrict__ bias,
                                             bf16_t* __restrict__ xb,
                                             bf16_t* __restrict__ Wt,
                                             bf16_t* __restrict__ vTb) {
  const int blk = blockIdx.x;
  const int xcd = blk & 7, j = blk >> 3;
  const int bt = xcd * 2 + (j & 1);
  const int c = j >> 1;
  const int t = threadIdx.x;
  const int w = t >> 6, lane = t & 63;
  const int mrow = lane & 15, kg = lane >> 4;
  const int b0 = bt * 16;

  const float* ax = x + (size_t)(b0 + mrow) * CK + w * 576;
  f32x4 acc = {0.f, 0.f, 0.f, 0.f};
  #pragma unroll 3
  for (int s = 0; s < 18; ++s) {
    const int koff = s * 32 + kg * 8;
    const float4 a0 = *(const float4*)(ax + koff);
    const float4 a1 = *(const float4*)(ax + koff + 4);
    bf16x8 af, bf;
    af[0] = (bf16_t)a0.x; af[1] = (bf16_t)a0.y; af[2] = (bf16_t)a0.z; af[3] = (bf16_t)a0.w;
    af[4] = (bf16_t)a1.x; af[5] = (bf16_t)a1.y; af[6] = (bf16_t)a1.z; af[7] = (bf16_t)a1.w;
    const int r = w * 72 + s * 4 + kg;
    const float4* wp = (const float4*)(W + (((size_t)r * CC + c) * CO + mrow) * CI);
    const float4 w0 = wp[0], w1 = wp[1];
    bf[0] = (bf16_t)w0.x; bf[1] = (bf16_t)w0.y; bf[2] = (bf16_t)w0.z; bf[3] = (bf16_t)w0.w;
    bf[4] = (bf16_t)w1.x; bf[5] = (bf16_t)w1.y; bf[6] = (bf16_t)w1.z; bf[7] = (bf16_t)w1.w;
    if (c == 0)  *(bf16x8*)(xb + (size_t)(b0 + mrow) * CK + w * 576 + koff) = af;
    if (bt == 0) *(bf16x8*)(Wt + ((size_t)c * CO + mrow) * CK + w * 576 + koff) = bf;
    acc = __builtin_amdgcn_mfma_f32_16x16x32_bf16(af, bf, acc, 0, 0, 0);
  }

  __shared__ float Ls[16][64][4];
  #pragma unroll
  for (int reg = 0; reg < 4; ++reg) Ls[w][lane][reg] = acc[reg];
  __syncthreads();
  if (t < 256) {
    const int row = t >> 4, col = t & 15;
    const int l = ((row >> 2) << 4) | col, reg = row & 3;
    float s = 0.f;
    #pragma unroll
    for (int q = 0; q < 16; ++q) s += Ls[q][l][reg];
    s = s * 0.1f + bias[c * CO + col];       // uniform c_ij = 1/10
    float n2 = s * s;
    #pragma unroll
    for (int m = 1; m < 16; m <<= 1) n2 += __shfl_xor(n2, m);
    const float vv = s * n2 / (1.f + n2) * rsqrtf(n2 + 1e-8f);
    vTb[(size_t)(c * CO + col) * CB + b0 + row] = (bf16_t)vv;
  }
}

// ---------------- s1/s2: pure MFMA from xb / Wts ----------------
template<bool LAST>
__global__ __launch_bounds__(1024) void k_s(const bf16_t* __restrict__ xb,
                                            const bf16_t* __restrict__ Wts,
                                            const float* __restrict__ bias,
                                            bf16_t* __restrict__ vTb,
                                            float* __restrict__ out) {
  const int blk = blockIdx.x;
  const int xcd = blk & 7, j = blk >> 3;
  const int bt = xcd * 2 + (j & 1);
  const int c = j >> 1;
  const int t = threadIdx.x;
  const int w = t >> 6, lane = t & 63;
  const int mrow = lane & 15, kg = lane >> 4;
  const int b0 = bt * 16;

  const bf16x8* ap = (const bf16x8*)(xb + (size_t)(b0 + mrow) * CK + w * 576) + kg;
  const bf16x8* bp = (const bf16x8*)(Wts + ((size_t)c * CO + mrow) * CK + w * 576) + kg;
  f32x4 acc0 = {0.f, 0.f, 0.f, 0.f}, acc1 = {0.f, 0.f, 0.f, 0.f};
  #pragma unroll
  for (int s = 0; s < 18; s += 2) {
    acc0 = __builtin_amdgcn_mfma_f32_16x16x32_bf16(ap[s * 4], bp[s * 4], acc0, 0, 0, 0);
    acc1 = __builtin_amdgcn_mfma_f32_16x16x32_bf16(ap[(s + 1) * 4], bp[(s + 1) * 4], acc1, 0, 0, 0);
  }
  const f32x4 acc = acc0 + acc1;

  __shared__ float Ls[16][64][4];
  #pragma unroll
  for (int reg = 0; reg < 4; ++reg) Ls[w][lane][reg] = acc[reg];
  __syncthreads();
  if (t < 256) {
    const int row = t >> 4, col = t & 15;
    const int l = ((row >> 2) << 4) | col, reg = row & 3;
    float s = 0.f;
    #pragma unroll
    for (int q = 0; q < 16; ++q) s += Ls[q][l][reg];
    s += bias[c * CO + col];
    float n2 = s * s;
    #pragma unroll
    for (int m = 1; m < 16; m <<= 1) n2 += __shfl_xor(n2, m);
    const float vv = s * n2 / (1.f + n2) * rsqrtf(n2 + 1e-8f);
    if (LAST) out[(size_t)(b0 + row) * NCO + c * CO + col] = vv;
    else      vTb[(size_t)(c * CO + col) * CB + b0 + row] = (bf16_t)vv;
  }
}

// ---------------- agree + softmax + W-prescale: 144 blocks x 512 thr ----------------
// stages x-slice (fp32->bf16 LDS transpose) + vTb; G via MFMA (K=b=256);
// agree -> b_ij -> softmax -> Wts[co][k] = Wt * cw for this block's 8 r's.
template<bool FIRST>
__global__ __launch_bounds__(512) void k_asc(const float* __restrict__ x,
                                             const float* __restrict__ W,
                                             const bf16_t* __restrict__ vTb,
                                             const bf16_t* __restrict__ Wt,
                                             float* __restrict__ b_ij,
                                             bf16_t* __restrict__ Wts) {
  const int r0 = blockIdx.x * 8;
  const int t = threadIdx.x;
  const int h = t >> 8;            // class-half 0/1
  const int th = t & 255;
  const int w = th >> 6, lane = th & 63;
  const int mrow = lane & 15, kg = lane >> 4;

  __shared__ __align__(16) unsigned short vL[NCO][CB + 8];   // 84.5 KB
  __shared__ __align__(16) unsigned short xTl[64][CB + 8];   // 33.8 KB
  __shared__ float agrL[8][CC];
  __shared__ float cwL[8][CC];

  #pragma unroll
  for (int q = 0; q < 10; ++q) {   // stage vTb (5120 bf16x8)
    const int idx = q * 512 + t;
    const int co = idx >> 5, bs = idx & 31;
    const bf16x8 v = ((const bf16x8*)vTb)[idx];
    *(bf16x8*)&vL[co][bs * 8] = v;
  }
  #pragma unroll
  for (int chunk = 0; chunk < 16; ++chunk) {  // stage xTl[ri][b] = bf16(x[b][r0*8+ri])
    const int b = chunk * 16 + (t >> 5);
    const int ri = (t & 31) * 2;
    const float2 v = *(const float2*)(x + (size_t)b * CK + r0 * 8 + ri);
    xTl[ri][b] = bfbits(v.x);
    xTl[ri + 1][b] = bfbits(v.y);
  }
  __syncthreads();

  bf16x8 a[8];
  #pragma unroll
  for (int s = 0; s < 8; ++s)
    a[s] = *(const bf16x8*)&xTl[w * 16 + mrow][s * 32 + kg * 8];

  const int o = lane & 15, g = lane >> 4;
  #pragma unroll
  for (int cc = 0; cc < 5; ++cc) {
    const int c = h * 5 + cc;
    f32x4 acc = {0.f, 0.f, 0.f, 0.f};
    #pragma unroll
    for (int s = 0; s < 8; ++s) {
      const bf16x8 bv = *(const bf16x8*)&vL[c * CO + mrow][s * 32 + kg * 8];
      acc = __builtin_amdgcn_mfma_f32_16x16x32_bf16(a[s], bv, acc, 0, 0, 0);
    }
    float p = 0.f;
    #pragma unroll
    for (int reg = 0; reg < 4; ++reg) {
      const int m = g * 4 + reg, rl = m >> 3, i = m & 7;
      p += acc[reg] * W[(((size_t)(r0 + w * 2 + rl) * CC + c) * CO + o) * CI + i];
    }
    #pragma unroll
    for (int msk = 1; msk < 32; msk <<= 1) p += __shfl_xor(p, msk);
    if ((lane & 31) == 0) agrL[w * 2 + (lane >> 5)][c] = p * (1.0f / CB);
  }
  __syncthreads();

  if (t < 8) {
    const int r = r0 + t;
    float nb[CC];
    float mx = -1e30f;
    #pragma unroll
    for (int c = 0; c < CC; ++c) {
      nb[c] = (FIRST ? 0.f : b_ij[r * CC + c]) + agrL[t][c];
      mx = fmaxf(mx, nb[c]);
    }
    float sum = 0.f;
    #pragma unroll
    for (int c = 0; c < CC; ++c) {
      b_ij[r * CC + c] = nb[c];
      const float e = __expf(nb[c] - mx);
      cwL[t][c] = e;
      sum += e;
    }
    const float inv = 1.f / sum;
    #pragma unroll
    for (int c = 0; c < CC; ++c) cwL[t][c] *= inv;
  }
  __syncthreads();

  #pragma unroll
  for (int q = 0; q < 3; ++q) {   // Wts = Wt * cw for this block's 8 r's (1280 slots)
    const int slot = q * 512 + t;
    if (slot < 1280) {
      const int co = slot >> 3, rl = slot & 7;
      const float cw = cwL[rl][co >> 4];
      const size_t off = (size_t)co * CK + (r0 + rl) * 8;
      const bf16x8 wv = *(const bf16x8*)(Wt + off);
      bf16x8 ov;
      #pragma unroll
      for (int jj = 0; jj < 8; ++jj) ov[jj] = (bf16_t)((float)wv[jj] * cw);
      *(bf16x8*)(Wts + off) = ov;
    }
  }
}

extern "C" void kernel_launch(void* const* d_in, const int* in_sizes, int n_in,
                              void* d_out, int out_size, void* d_ws, size_t ws_size,
                              hipStream_t stream) {
  const float* x    = (const float*)d_in[0];
  const float* W    = (const float*)d_in[1];
  const float* bias = (const float*)d_in[2];
  float* out = (float*)d_out;

  // ws: xb | Wt | Wts | vTb (bf16) | b_ij (f32)   (~10.7 MB)
  bf16_t* xb  = (bf16_t*)d_ws;
  bf16_t* Wt  = xb  + (size_t)CB * CK;
  bf16_t* Wts = Wt  + (size_t)NCO * CK;
  bf16_t* vTb = Wts + (size_t)NCO * CK;
  float*  b_ij = (float*)(vTb + (size_t)NCO * CB);

  // iter 0: fused cvt + s (side-writes xb, Wt), then agree+softmax+prescale
  k_s0<<<160, 1024, 0, stream>>>(x, W, bias, xb, Wt, vTb);
  k_asc<true><<<144, 512, 0, stream>>>(x, W, vTb, Wt, b_ij, Wts);

  // iter 1
  k_s<false><<<160, 1024, 0, stream>>>(xb, Wts, bias, vTb, out);
  k_asc<false><<<144, 512, 0, stream>>>(x, W, vTb, Wt, b_ij, Wts);

  // iter 2 (final -> out)
  k_s<true><<<160, 1024, 0, stream>>>(xb, Wts, bias, vTb, out);
}

// Round 12
// 85.152 us; speedup vs baseline: 2.4380x; 1.1448x over previous
//
#include <hip/hip_runtime.h>

#define CB 256   // batch
#define CR 1152  // routes
#define CC 10    // class capsules
#define CO 16    // out dim
#define CI 8     // in dim
#define CK (CR*CI)   // 9216
#define NCO (CC*CO)  // 160

typedef __bf16 bf16_t;
typedef __attribute__((ext_vector_type(8))) __bf16 bf16x8;
typedef __attribute__((ext_vector_type(4))) float f32x4;

__device__ __forceinline__ unsigned short bfbits(float f) {
  union { __bf16 h; unsigned short u; } u; u.h = (bf16_t)f; return u.u;
}

// ---------------- s0: fused cvt + s + squash (iter 0, uniform c_ij) ----------------
// 160 blocks = (16 bt, 10 c), 1024 thr = 16 waves x 576 k (18 MFMA steps).
// Batched loads (6 steps in flight) for ILP; side-writes of xb/Wt distributed
// across ALL blocks by (w,s)-cell hashing (cell%10==c -> xb, cell%16==bt -> Wt).
__global__ __launch_bounds__(1024) void k_s0(const float* __restrict__ x,
                                             const float* __restrict__ W,
                                             const float* __restrict__ bias,
                                             bf16_t* __restrict__ xb,
                                             bf16_t* __restrict__ Wt,
                                             bf16_t* __restrict__ vTb) {
  const int blk = blockIdx.x;
  const int xcd = blk & 7, j = blk >> 3;
  const int bt = xcd * 2 + (j & 1);
  const int c = j >> 1;
  const int t = threadIdx.x;
  const int w = t >> 6, lane = t & 63;
  const int mrow = lane & 15, kg = lane >> 4;
  const int b0 = bt * 16;

  const float* ax = x + (size_t)(b0 + mrow) * CK + w * 576;
  f32x4 acc = {0.f, 0.f, 0.f, 0.f};

  #pragma unroll
  for (int batch = 0; batch < 3; ++batch) {
    float4 xa[6][2], wa[6][2];
    #pragma unroll
    for (int s6 = 0; s6 < 6; ++s6) {
      const int s = batch * 6 + s6;
      const int koff = s * 32 + kg * 8;
      xa[s6][0] = *(const float4*)(ax + koff);
      xa[s6][1] = *(const float4*)(ax + koff + 4);
      const int r = w * 72 + s * 4 + kg;
      const float4* wp = (const float4*)(W + (((size_t)r * CC + c) * CO + mrow) * CI);
      wa[s6][0] = wp[0];
      wa[s6][1] = wp[1];
    }
    #pragma unroll
    for (int s6 = 0; s6 < 6; ++s6) {
      const int s = batch * 6 + s6;
      const int koff = s * 32 + kg * 8;
      const int cell = w * 18 + s;
      bf16x8 af, bf;
      af[0] = (bf16_t)xa[s6][0].x; af[1] = (bf16_t)xa[s6][0].y;
      af[2] = (bf16_t)xa[s6][0].z; af[3] = (bf16_t)xa[s6][0].w;
      af[4] = (bf16_t)xa[s6][1].x; af[5] = (bf16_t)xa[s6][1].y;
      af[6] = (bf16_t)xa[s6][1].z; af[7] = (bf16_t)xa[s6][1].w;
      bf[0] = (bf16_t)wa[s6][0].x; bf[1] = (bf16_t)wa[s6][0].y;
      bf[2] = (bf16_t)wa[s6][0].z; bf[3] = (bf16_t)wa[s6][0].w;
      bf[4] = (bf16_t)wa[s6][1].x; bf[5] = (bf16_t)wa[s6][1].y;
      bf[6] = (bf16_t)wa[s6][1].z; bf[7] = (bf16_t)wa[s6][1].w;
      if (cell % 10 == c)  *(bf16x8*)(xb + (size_t)(b0 + mrow) * CK + w * 576 + koff) = af;
      if (cell % 16 == bt) *(bf16x8*)(Wt + ((size_t)c * CO + mrow) * CK + w * 576 + koff) = bf;
      acc = __builtin_amdgcn_mfma_f32_16x16x32_bf16(af, bf, acc, 0, 0, 0);
    }
  }

  __shared__ float Ls[16][64][4];
  #pragma unroll
  for (int reg = 0; reg < 4; ++reg) Ls[w][lane][reg] = acc[reg];
  __syncthreads();
  if (t < 256) {
    const int row = t >> 4, col = t & 15;
    const int l = ((row >> 2) << 4) | col, reg = row & 3;
    float s = 0.f;
    #pragma unroll
    for (int q = 0; q < 16; ++q) s += Ls[q][l][reg];
    s = s * 0.1f + bias[c * CO + col];       // uniform c_ij = 1/10
    float n2 = s * s;
    #pragma unroll
    for (int m = 1; m < 16; m <<= 1) n2 += __shfl_xor(n2, m);
    const float vv = s * n2 / (1.f + n2) * rsqrtf(n2 + 1e-8f);
    vTb[(size_t)(c * CO + col) * CB + b0 + row] = (bf16_t)vv;
  }
}

// ---------------- s1/s2: pure MFMA from xb / Wts ----------------
template<bool LAST>
__global__ __launch_bounds__(1024) void k_s(const bf16_t* __restrict__ xb,
                                            const bf16_t* __restrict__ Wts,
                                            const float* __restrict__ bias,
                                            bf16_t* __restrict__ vTb,
                                            float* __restrict__ out) {
  const int blk = blockIdx.x;
  const int xcd = blk & 7, j = blk >> 3;
  const int bt = xcd * 2 + (j & 1);
  const int c = j >> 1;
  const int t = threadIdx.x;
  const int w = t >> 6, lane = t & 63;
  const int mrow = lane & 15, kg = lane >> 4;
  const int b0 = bt * 16;

  const bf16x8* ap = (const bf16x8*)(xb + (size_t)(b0 + mrow) * CK + w * 576) + kg;
  const bf16x8* bp = (const bf16x8*)(Wts + ((size_t)c * CO + mrow) * CK + w * 576) + kg;
  f32x4 acc0 = {0.f, 0.f, 0.f, 0.f}, acc1 = {0.f, 0.f, 0.f, 0.f};
  #pragma unroll
  for (int s = 0; s < 18; s += 2) {
    acc0 = __builtin_amdgcn_mfma_f32_16x16x32_bf16(ap[s * 4], bp[s * 4], acc0, 0, 0, 0);
    acc1 = __builtin_amdgcn_mfma_f32_16x16x32_bf16(ap[(s + 1) * 4], bp[(s + 1) * 4], acc1, 0, 0, 0);
  }
  const f32x4 acc = acc0 + acc1;

  __shared__ float Ls[16][64][4];
  #pragma unroll
  for (int reg = 0; reg < 4; ++reg) Ls[w][lane][reg] = acc[reg];
  __syncthreads();
  if (t < 256) {
    const int row = t >> 4, col = t & 15;
    const int l = ((row >> 2) << 4) | col, reg = row & 3;
    float s = 0.f;
    #pragma unroll
    for (int q = 0; q < 16; ++q) s += Ls[q][l][reg];
    s += bias[c * CO + col];
    float n2 = s * s;
    #pragma unroll
    for (int m = 1; m < 16; m <<= 1) n2 += __shfl_xor(n2, m);
    const float vv = s * n2 / (1.f + n2) * rsqrtf(n2 + 1e-8f);
    if (LAST) out[(size_t)(b0 + row) * NCO + c * CO + col] = vv;
    else      vTb[(size_t)(c * CO + col) * CB + b0 + row] = (bf16_t)vv;
  }
}

// ---------------- agree + softmax + W-prescale: 144 blocks x 512 thr ----------------
template<bool FIRST>
__global__ __launch_bounds__(512) void k_asc(const float* __restrict__ x,
                                             const float* __restrict__ W,
                                             const bf16_t* __restrict__ vTb,
                                             const bf16_t* __restrict__ Wt,
                                             float* __restrict__ b_ij,
                                             bf16_t* __restrict__ Wts) {
  const int r0 = blockIdx.x * 8;
  const int t = threadIdx.x;
  const int h = t >> 8;            // class-half 0/1
  const int th = t & 255;
  const int w = th >> 6, lane = th & 63;
  const int mrow = lane & 15, kg = lane >> 4;

  __shared__ __align__(16) unsigned short vL[NCO][CB + 8];   // 84.5 KB
  __shared__ __align__(16) unsigned short xTl[64][CB + 8];   // 33.8 KB
  __shared__ float agrL[8][CC];
  __shared__ float cwL[8][CC];

  #pragma unroll
  for (int q = 0; q < 10; ++q) {   // stage vTb (5120 bf16x8)
    const int idx = q * 512 + t;
    const int co = idx >> 5, bs = idx & 31;
    const bf16x8 v = ((const bf16x8*)vTb)[idx];
    *(bf16x8*)&vL[co][bs * 8] = v;
  }
  #pragma unroll
  for (int chunk = 0; chunk < 16; ++chunk) {  // stage xTl[ri][b] = bf16(x[b][r0*8+ri])
    const int b = chunk * 16 + (t >> 5);
    const int ri = (t & 31) * 2;
    const float2 v = *(const float2*)(x + (size_t)b * CK + r0 * 8 + ri);
    xTl[ri][b] = bfbits(v.x);
    xTl[ri + 1][b] = bfbits(v.y);
  }
  __syncthreads();

  bf16x8 a[8];
  #pragma unroll
  for (int s = 0; s < 8; ++s)
    a[s] = *(const bf16x8*)&xTl[w * 16 + mrow][s * 32 + kg * 8];

  const int o = lane & 15, g = lane >> 4;
  #pragma unroll
  for (int cc = 0; cc < 5; ++cc) {
    const int c = h * 5 + cc;
    f32x4 acc = {0.f, 0.f, 0.f, 0.f};
    #pragma unroll
    for (int s = 0; s < 8; ++s) {
      const bf16x8 bv = *(const bf16x8*)&vL[c * CO + mrow][s * 32 + kg * 8];
      acc = __builtin_amdgcn_mfma_f32_16x16x32_bf16(a[s], bv, acc, 0, 0, 0);
    }
    float p = 0.f;
    #pragma unroll
    for (int reg = 0; reg < 4; ++reg) {
      const int m = g * 4 + reg, rl = m >> 3, i = m & 7;
      p += acc[reg] * W[(((size_t)(r0 + w * 2 + rl) * CC + c) * CO + o) * CI + i];
    }
    #pragma unroll
    for (int msk = 1; msk < 32; msk <<= 1) p += __shfl_xor(p, msk);
    if ((lane & 31) == 0) agrL[w * 2 + (lane >> 5)][c] = p * (1.0f / CB);
  }
  __syncthreads();

  if (t < 8) {
    const int r = r0 + t;
    float nb[CC];
    float mx = -1e30f;
    #pragma unroll
    for (int c = 0; c < CC; ++c) {
      nb[c] = (FIRST ? 0.f : b_ij[r * CC + c]) + agrL[t][c];
      mx = fmaxf(mx, nb[c]);
    }
    float sum = 0.f;
    #pragma unroll
    for (int c = 0; c < CC; ++c) {
      b_ij[r * CC + c] = nb[c];
      const float e = __expf(nb[c] - mx);
      cwL[t][c] = e;
      sum += e;
    }
    const float inv = 1.f / sum;
    #pragma unroll
    for (int c = 0; c < CC; ++c) cwL[t][c] *= inv;
  }
  __syncthreads();

  #pragma unroll
  for (int q = 0; q < 3; ++q) {   // Wts = Wt * cw for this block's 8 r's (1280 slots)
    const int slot = q * 512 + t;
    if (slot < 1280) {
      const int co = slot >> 3, rl = slot & 7;
      const float cw = cwL[rl][co >> 4];
      const size_t off = (size_t)co * CK + (r0 + rl) * 8;
      const bf16x8 wv = *(const bf16x8*)(Wt + off);
      bf16x8 ov;
      #pragma unroll
      for (int jj = 0; jj < 8; ++jj) ov[jj] = (bf16_t)((float)wv[jj] * cw);
      *(bf16x8*)(Wts + off) = ov;
    }
  }
}

extern "C" void kernel_launch(void* const* d_in, const int* in_sizes, int n_in,
                              void* d_out, int out_size, void* d_ws, size_t ws_size,
                              hipStream_t stream) {
  const float* x    = (const float*)d_in[0];
  const float* W    = (const float*)d_in[1];
  const float* bias = (const float*)d_in[2];
  float* out = (float*)d_out;

  // ws: xb | Wt | Wts | vTb (bf16) | b_ij (f32)   (~10.7 MB)
  bf16_t* xb  = (bf16_t*)d_ws;
  bf16_t* Wt  = xb  + (size_t)CB * CK;
  bf16_t* Wts = Wt  + (size_t)NCO * CK;
  bf16_t* vTb = Wts + (size_t)NCO * CK;
  float*  b_ij = (float*)(vTb + (size_t)NCO * CB);

  // iter 0: fused cvt + s (distributed side-writes), then agree+softmax+prescale
  k_s0<<<160, 1024, 0, stream>>>(x, W, bias, xb, Wt, vTb);
  k_asc<true><<<144, 512, 0, stream>>>(x, W, vTb, Wt, b_ij, Wts);

  // iter 1
  k_s<false><<<160, 1024, 0, stream>>>(xb, Wts, bias, vTb, out);
  k_asc<false><<<144, 512, 0, stream>>>(x, W, vTb, Wt, b_ij, Wts);

  // iter 2 (final -> out)
  k_s<true><<<160, 1024, 0, stream>>>(xb, Wts, bias, vTb, out);
}